// Round 4
// baseline (100.437 us; speedup 1.0000x reference)
//
#include <hip/hip_runtime.h>
#include <math.h>

#define NS 4096
#define NT 4096
#define RPB 4                    // rows computed per block
#define CQ  4                    // column quarters
#define NBLK ((NS / RPB) * CQ)   // 4096 blocks

__device__ __forceinline__ double block_reduce(double v, int tid) {
    #pragma unroll
    for (int off = 32; off > 0; off >>= 1)
        v += __shfl_down(v, off, 64);
    __shared__ double lds[4];
    const int lane = tid & 63, wv = tid >> 6;
    if (lane == 0) lds[wv] = v;
    __syncthreads();
    return lds[0] + lds[1] + lds[2] + lds[3];   // valid in thread 0
}

// 4096 blocks: blockIdx = (row-group rg) * 4 + (column-quarter cb).
// Thread t owns ONE float4 at column j0 = cb*1024 + t*4 (perfectly coalesced:
// lane i reads base + i*16B). All 6 row-loads are issued up-front into w[6][4]
// so the global loads overlap instead of serializing per row iteration.
__global__ __launch_bounds__(256, 6) void bs_main(const float* __restrict__ V,
                                                  double* __restrict__ part,
                                                  float C1, float C2) {
    const int tid = threadIdx.x;
    const int cb  = blockIdx.x & (CQ - 1);
    const int rg  = blockIdx.x / CQ;
    const int r0  = rg * RPB;
    const int j0  = cb * (NT / CQ) + tid * 4;

    const float INV2DU = 2047.5f;      // 1/(2*DU)
    const float INVDU2 = 16769025.0f;  // 1/DU^2 = 4095^2
    const float INV2DT = 102375.0f;    // 1/(2*DT_NORM)
    const float AL     = 2.5f;         // 2r/sigma^2
    const float dL     = C2 - C1;

    // ---- issue all global loads up-front (6 rows + 2x4 edge scalars) ----
    float w[6][4];
    #pragma unroll
    for (int q = 0; q < 6; ++q) {
        int r = r0 - 1 + q;
        r = (r < 0) ? 0 : ((r > NS - 1) ? NS - 1 : r);
        const float4 x = *(const float4*)(V + (size_t)r * NT + j0);
        w[q][0] = x.x; w[q][1] = x.y; w[q][2] = x.z; w[q][3] = x.w;
    }
    float lf[RPB], rt[RPB];
    #pragma unroll
    for (int rr = 0; rr < RPB; ++rr) {
        const int r = r0 + rr;
        lf[rr] = (j0 > 0)      ? V[(size_t)r * NT + j0 - 1] : 0.0f;  // L1/L2 hit
        rt[rr] = (j0 + 4 < NT) ? V[(size_t)r * NT + j0 + 4] : 0.0f;  // L1/L2 hit
    }

    float pde = 0.0f;           // <=16 residual^2 per thread: f32 is plenty
    double bc = 0.0, tc = 0.0;

    #pragma unroll
    for (int rr = 0; rr < RPB; ++rr) {
        const int r = r0 + rr;
        const float* a = w[rr];
        const float* b = w[rr + 1];
        const float* c = w[rr + 2];

        // per-row stretch metrics in f32 (reference computes these in f32 JAX)
        const float u    = (float)r * (1.0f / (float)(NS - 1));
        const float L    = C2 * u + C1 * (1.0f - u);
        const float S    = 100.0f + 30.0f * (L * L * L * (1.0f / 6.0f) + L);
        const float dS   = 30.0f * dL * (0.5f * L * L + 1.0f);
        const float d2S  = 30.0f * dL * dL * L;
        const float Sn   = S   * (1.0f / 300.0f);
        const float Sun  = dS  * (1.0f / 300.0f);
        const float Suun = d2S * (1.0f / 300.0f);
        const float invSun  = 1.0f / Sun;
        const float invSun3 = invSun * invSun * invSun;
        const float Sn2 = Sn * Sn;
        const float ASn = AL * Sn;

        if (r >= 1 && r <= NS - 2) {
            #pragma unroll
            for (int k = 0; k < 4; ++k) {
                const int j = j0 + k;
                if (j >= 1 && j <= NT - 2) {
                    const float cm = (k == 0) ? lf[rr] : b[k - 1];
                    const float cp = (k == 3) ? rt[rr] : b[k + 1];
                    const float Vu  = (c[k] - a[k]) * INV2DU;
                    const float Vuu = (c[k] - 2.0f * b[k] + a[k]) * INVDU2;
                    const float Vt  = (cp - cm) * INV2DT;
                    const float VS  = Vu * invSun;
                    float VSS = (Vuu * Sun - Vu * Suun) * invSun3;
                    VSS = fminf(fmaxf(VSS, -100.0f), 100.0f);
                    const float res = Vt - Sn2 * VSS - ASn * VS + AL * b[k];
                    pde += res * res;
                }
            }
        }

        if (r == NS - 1) {
            // far-field BC at S=Smax (only rg == NS/RPB-1 blocks reach this)
            #pragma unroll
            for (int k = 0; k < 4; ++k) {
                const float t   = (float)(j0 + k) * (1.0f / (float)(NT - 1));
                const float tgt = 1.0f - (100.0f / 300.0f) * expf(-0.05f * (1.0f - t));
                const float d   = b[k] - tgt;
                bc += (double)(d * d);
            }
        }

        if (cb == CQ - 1 && tid == 255) {
            // terminal condition element V[r, NT-1] == b[3]
            const float x  = 50.0f * (u - 100.0f / 300.0f);
            const float sp = fmaxf(x, 0.0f) + log1pf(expf(-fabsf(x)));
            const float payoff = sp * (1.0f / 50.0f);
            const float d  = b[3] - payoff;
            const float ad = fabsf(d);
            tc += (double)((ad < 0.01f) ? 0.5f * d * d : 0.01f * (ad - 0.005f));
        }
    }

    const double n_int = (double)(NS - 2) * (double)(NT - 2);
    double contrib = (double)pde * (1.0 / n_int)
                   + bc * (10.0 / (double)NT)
                   + tc * (10.0 / (double)NS);

    contrib = block_reduce(contrib, tid);
    if (tid == 0) part[blockIdx.x] = contrib;
}

__global__ __launch_bounds__(256) void bs_final(const double* __restrict__ part,
                                                float* __restrict__ out) {
    const int tid = threadIdx.x;
    double s = 0.0;
    for (int idx = tid; idx < NBLK; idx += 256) s += part[idx];
    s = block_reduce(s, tid);
    if (tid == 0) out[0] = (float)s;
}

// Host-side faithful port of CubicStretching._solve_depressed_cubic.
static double cubic_root_host(double Q) {
    const double p = 6.0;                 // CHI
    const double q = p * Q;               // CHI * Q
    const double sp = sqrt(p);
    double arg = fabs(q) / (2.0 * p * sp / (3.0 * sqrt(3.0)));
    if (arg < 1.0) arg = 1.0;
    const double c = 2.0 * sp * cosh(acosh(arg) / 3.0);
    return (q >= 0.0) ? -c : c;
}

extern "C" void kernel_launch(void* const* d_in, const int* in_sizes, int n_in,
                              void* d_out, int out_size, void* d_ws, size_t ws_size,
                              hipStream_t stream) {
    const float* V  = (const float*)d_in[0];
    float* out      = (float*)d_out;
    double* part    = (double*)d_ws;   // NBLK doubles, all written every launch

    const double C1 = cubic_root_host((100.0 - 0.0)   / 30.0);
    const double C2 = cubic_root_host((100.0 - 300.0) / 30.0);

    bs_main <<<NBLK, 256, 0, stream>>>(V, part, (float)C1, (float)C2);
    bs_final<<<1,    256, 0, stream>>>(part, out);
}